// Round 4
// baseline (140.832 us; speedup 1.0000x reference)
//
#include <hip/hip_runtime.h>
#include <cstddef>
#include <cstdint>

constexpr int BATCH   = 4096;
constexpr int IN_DIM  = 8192;
constexpr int OUT_DIM = 16384;
constexpr int THREADS = 1024;                       // 16 waves per block
constexpr int NBLK    = 256;                        // persistent: 1 block/CU
constexpr int PAIRS   = (BATCH / 2) / NBLK;         // 8 row-pairs per block
constexpr int OPT     = 4;                          // outputs per thread per iter
constexpr int ITERS   = OUT_DIM / (THREADS * OPT);  // 4
constexpr int SSTEPS  = (IN_DIM / 2) / THREADS;     // 4 staging steps (float2)

// clang-native vector types (accepted by __builtin_nontemporal_*)
typedef float f32x2 __attribute__((ext_vector_type(2)));
typedef float f32x4 __attribute__((ext_vector_type(4)));

// softmax over 16 gate logits collapsed to (c0, ca, cb, cab)
__device__ __forceinline__ float4 softmax_coef(const float* __restrict__ wrow) {
  const float4* wp = reinterpret_cast<const float4*>(wrow);
  float4 t0 = wp[0], t1 = wp[1], t2 = wp[2], t3 = wp[3];
  float w[16] = { t0.x, t0.y, t0.z, t0.w,
                  t1.x, t1.y, t1.z, t1.w,
                  t2.x, t2.y, t2.z, t2.w,
                  t3.x, t3.y, t3.z, t3.w };
  float m = w[0];
#pragma unroll
  for (int i = 1; i < 16; ++i) m = fmaxf(m, w[i]);
  float p[16];
  float s = 0.f;
#pragma unroll
  for (int i = 0; i < 16; ++i) { p[i] = __expf(w[i] - m); s += p[i]; }
  const float inv = 1.0f / s;
  const float GC[16]  = {0,0,0,0, 0,0,0,0, 1,1,1,1, 1,1,1,1};
  const float GA[16]  = {0,0,1,1, 0,0,1,1, -1,-1,0,0, -1,-1,0,0};
  const float GB[16]  = {0,0,0,0, 1,1,1,1, -1,-1,-1,-1, 0,0,0,0};
  const float GAB[16] = {0,1,-1,0, -1,0,-2,-1, 1,2,0,1, 0,1,-1,0};
  float c0 = 0.f, ca = 0.f, cb = 0.f, cab = 0.f;
#pragma unroll
  for (int i = 0; i < 16; ++i) {
    c0  += p[i] * GC[i];
    ca  += p[i] * GA[i];
    cb  += p[i] * GB[i];
    cab += p[i] * GAB[i];
  }
  return make_float4(c0 * inv, ca * inv, cb * inv, cab * inv);
}

__global__ __launch_bounds__(256)
void coef_kernel(const float* __restrict__ weights, float4* __restrict__ coef) {
  const int o = blockIdx.x * 256 + threadIdx.x;
  if (o < OUT_DIM) coef[o] = softmax_coef(weights + (size_t)o * 16);
}

__global__ __launch_bounds__(THREADS)
void logic_main(const float* __restrict__ x,
                const float4* __restrict__ coef,
                const int* __restrict__ idx_a,
                const int* __restrict__ idx_b,
                float* __restrict__ out) {
  // double-buffered pair-interleaved x:
  // xpair[buf][i] = { r0[2i], r1[2i], r0[2i+1], r1[2i+1] }
  __shared__ float4 xpair[2][IN_DIM / 2];            // 2 x 64 KB = 128 KB

  const int t    = threadIdx.x;
  const int row0 = blockIdx.x * (2 * PAIRS);         // 16 contiguous rows per block

  f32x2 la[SSTEPS], lb[SSTEPS];                      // in-flight staging regs

  // ---- prologue: stage pair 0 into buffer 0 ----
  {
    const f32x2* __restrict__ r0 =
        reinterpret_cast<const f32x2*>(x + (size_t)row0 * IN_DIM);
    const f32x2* __restrict__ r1 =
        reinterpret_cast<const f32x2*>(x + (size_t)(row0 + 1) * IN_DIM);
#pragma unroll
    for (int s = 0; s < SSTEPS; ++s) {
      const int q = s * THREADS + t;
      la[s] = __builtin_nontemporal_load(r0 + q);
      lb[s] = __builtin_nontemporal_load(r1 + q);
    }
#pragma unroll
    for (int s = 0; s < SSTEPS; ++s) {
      const int q = s * THREADS + t;
      xpair[0][q] = make_float4(la[s].x, lb[s].x, la[s].y, lb[s].y);
    }
  }
  __syncthreads();

  for (int p = 0; p < PAIRS; ++p) {
    const int b0 = row0 + 2 * p;
    const float2* __restrict__ pr =
        reinterpret_cast<const float2*>(&xpair[p & 1][0]);

    // ---- issue next pair's loads EARLY (latency hides under compute) ----
    if (p + 1 < PAIRS) {
      const f32x2* __restrict__ r0 =
          reinterpret_cast<const f32x2*>(x + (size_t)(b0 + 2) * IN_DIM);
      const f32x2* __restrict__ r1 =
          reinterpret_cast<const f32x2*>(x + (size_t)(b0 + 3) * IN_DIM);
#pragma unroll
      for (int s = 0; s < SSTEPS; ++s) {
        const int q = s * THREADS + t;
        la[s] = __builtin_nontemporal_load(r0 + q);
        lb[s] = __builtin_nontemporal_load(r1 + q);
      }
    }

    // ---- compute current pair: gather + affine + NT store ----
#pragma unroll
    for (int it = 0; it < ITERS; ++it) {
      const int o = it * (THREADS * OPT) + t * OPT;

      const int4 ia = *reinterpret_cast<const int4*>(idx_a + o);
      const int4 ib = *reinterpret_cast<const int4*>(idx_b + o);
      const float4 c0 = coef[o + 0], c1 = coef[o + 1],
                   c2 = coef[o + 2], c3 = coef[o + 3];

      // one ds_read_b64 per operand serves BOTH rows
      const float2 A0 = pr[ia.x], A1 = pr[ia.y], A2 = pr[ia.z], A3 = pr[ia.w];
      const float2 B0 = pr[ib.x], B1 = pr[ib.y], B2 = pr[ib.z], B3 = pr[ib.w];

      f32x4 res0, res1;
      res0.x = fmaf(fmaf(c0.w, A0.x, c0.z), B0.x, fmaf(c0.y, A0.x, c0.x));
      res1.x = fmaf(fmaf(c0.w, A0.y, c0.z), B0.y, fmaf(c0.y, A0.y, c0.x));
      res0.y = fmaf(fmaf(c1.w, A1.x, c1.z), B1.x, fmaf(c1.y, A1.x, c1.x));
      res1.y = fmaf(fmaf(c1.w, A1.y, c1.z), B1.y, fmaf(c1.y, A1.y, c1.x));
      res0.z = fmaf(fmaf(c2.w, A2.x, c2.z), B2.x, fmaf(c2.y, A2.x, c2.x));
      res1.z = fmaf(fmaf(c2.w, A2.y, c2.z), B2.y, fmaf(c2.y, A2.y, c2.x));
      res0.w = fmaf(fmaf(c3.w, A3.x, c3.z), B3.x, fmaf(c3.y, A3.x, c3.x));
      res1.w = fmaf(fmaf(c3.w, A3.y, c3.z), B3.y, fmaf(c3.y, A3.y, c3.x));

      __builtin_nontemporal_store(
          res0, reinterpret_cast<f32x4*>(out + (size_t)b0 * OUT_DIM + o));
      __builtin_nontemporal_store(
          res1, reinterpret_cast<f32x4*>(out + (size_t)(b0 + 1) * OUT_DIM + o));
    }
    __syncthreads();   // everyone done reading xpair[p&1]; prior buffer free

    // ---- write next pair into the other buffer (reads finished 2 barriers ago) ----
    if (p + 1 < PAIRS) {
#pragma unroll
      for (int s = 0; s < SSTEPS; ++s) {
        const int q = s * THREADS + t;
        xpair[(p + 1) & 1][q] = make_float4(la[s].x, lb[s].x, la[s].y, lb[s].y);
      }
      __syncthreads();
    }
  }
}

extern "C" void kernel_launch(void* const* d_in, const int* in_sizes, int n_in,
                              void* d_out, int out_size, void* d_ws, size_t ws_size,
                              hipStream_t stream) {
  const float* x       = (const float*)d_in[0];
  const float* weights = (const float*)d_in[1];
  const int*   idx_a   = (const int*)d_in[2];
  const int*   idx_b   = (const int*)d_in[3];
  float*       out     = (float*)d_out;

  float4* coef = (float4*)d_ws;   // 256 KB scratch
  coef_kernel<<<OUT_DIM / 256, 256, 0, stream>>>(weights, coef);
  logic_main<<<NBLK, THREADS, 0, stream>>>(x, coef, idx_a, idx_b, out);
}

// Round 5
// 106.562 us; speedup vs baseline: 1.3216x; 1.3216x over previous
//
#include <hip/hip_runtime.h>
#include <cstddef>
#include <cstdint>

constexpr int BATCH   = 4096;
constexpr int IN_DIM  = 8192;
constexpr int OUT_DIM = 16384;
constexpr int THREADS = 256;                        // 4 waves per block
constexpr int NBLK    = BATCH / 2;                  // 2048 blocks, one row-pair each
constexpr int OPT     = 4;                          // outputs per thread per iter
constexpr int ITERS   = OUT_DIM / (THREADS * OPT);  // 16
constexpr int SSTEPS  = (IN_DIM / 2) / THREADS;     // 16 staging steps (f32x2 per row)

typedef float    f32x2 __attribute__((ext_vector_type(2)));
typedef float    f32x4 __attribute__((ext_vector_type(4)));
typedef uint32_t u32x2 __attribute__((ext_vector_type(2)));

__device__ __forceinline__ uint32_t f2bf(float f) {   // RNE bf16 (x>=0, no NaN here)
  uint32_t u = __float_as_uint(f);
  u += 0x7fffu + ((u >> 16) & 1u);
  return u >> 16;
}
__device__ __forceinline__ uint32_t pack_bf(float a, float b) {
  return f2bf(a) | (f2bf(b) << 16);
}
__device__ __forceinline__ float bf_lo(uint32_t u) { return __uint_as_float(u << 16); }
__device__ __forceinline__ float bf_hi(uint32_t u) { return __uint_as_float(u & 0xffff0000u); }

// softmax over 16 gate logits collapsed to (c0, ca, cb, cab); also packs idx pair
__global__ __launch_bounds__(256)
void coef_kernel(const float* __restrict__ weights,
                 const int* __restrict__ idx_a,
                 const int* __restrict__ idx_b,
                 float4* __restrict__ coef,
                 uint32_t* __restrict__ pidx) {
  const int o = blockIdx.x * 256 + threadIdx.x;
  if (o >= OUT_DIM) return;

  const float4* wp = reinterpret_cast<const float4*>(weights + (size_t)o * 16);
  float4 t0 = wp[0], t1 = wp[1], t2 = wp[2], t3 = wp[3];
  float w[16] = { t0.x, t0.y, t0.z, t0.w, t1.x, t1.y, t1.z, t1.w,
                  t2.x, t2.y, t2.z, t2.w, t3.x, t3.y, t3.z, t3.w };
  float m = w[0];
#pragma unroll
  for (int i = 1; i < 16; ++i) m = fmaxf(m, w[i]);
  float p[16]; float s = 0.f;
#pragma unroll
  for (int i = 0; i < 16; ++i) { p[i] = __expf(w[i] - m); s += p[i]; }
  const float inv = 1.0f / s;
  const float GC[16]  = {0,0,0,0, 0,0,0,0, 1,1,1,1, 1,1,1,1};
  const float GA[16]  = {0,0,1,1, 0,0,1,1, -1,-1,0,0, -1,-1,0,0};
  const float GB[16]  = {0,0,0,0, 1,1,1,1, -1,-1,-1,-1, 0,0,0,0};
  const float GAB[16] = {0,1,-1,0, -1,0,-2,-1, 1,2,0,1, 0,1,-1,0};
  float c0 = 0.f, ca = 0.f, cb = 0.f, cab = 0.f;
#pragma unroll
  for (int i = 0; i < 16; ++i) {
    c0 += p[i] * GC[i]; ca += p[i] * GA[i];
    cb += p[i] * GB[i]; cab += p[i] * GAB[i];
  }
  coef[o] = make_float4(c0 * inv, ca * inv, cb * inv, cab * inv);
  pidx[o] = (uint32_t)idx_a[o] | ((uint32_t)idx_b[o] << 16);
}

__global__ __launch_bounds__(THREADS)
void logic_main(const float* __restrict__ x,
                const float4* __restrict__ coef,
                const uint32_t* __restrict__ pidx,
                float* __restrict__ out) {
  // xp[i] = { bf16 x[b0][i] (lo), bf16 x[b1][i] (hi) } -> 32 KB, 5 blocks/CU
  __shared__ uint32_t xp[IN_DIM];

  const int t  = threadIdx.x;
  const int b0 = blockIdx.x * 2;

  const f32x2* __restrict__ r0 =
      reinterpret_cast<const f32x2*>(x + (size_t)b0 * IN_DIM);
  const f32x2* __restrict__ r1 =
      reinterpret_cast<const f32x2*>(x + (size_t)(b0 + 1) * IN_DIM);

  // ---- stage row-pair as packed bf16 (NT loads: x has zero reuse) ----
#pragma unroll
  for (int s = 0; s < SSTEPS; ++s) {
    const int q = s * THREADS + t;                 // f32x2 index (elements 2q, 2q+1)
    f32x2 a = __builtin_nontemporal_load(r0 + q);
    f32x2 b = __builtin_nontemporal_load(r1 + q);
    u32x2 pk;
    pk.x = pack_bf(a.x, b.x);
    pk.y = pack_bf(a.y, b.y);
    *reinterpret_cast<u32x2*>(&xp[2 * q]) = pk;    // ds_write_b64
  }
  __syncthreads();

#pragma unroll 4
  for (int it = 0; it < ITERS; ++it) {
    const int o = it * (THREADS * OPT) + t * OPT;

    const int4 pi = *reinterpret_cast<const int4*>(pidx + o);
    const float4 c0 = coef[o + 0], c1 = coef[o + 1],
                 c2 = coef[o + 2], c3 = coef[o + 3];

    // one ds_read_b32 per operand serves BOTH rows (bf16 pair)
    const uint32_t ga0 = xp[(uint32_t)pi.x & 0xffffu], gb0 = xp[(uint32_t)pi.x >> 16];
    const uint32_t ga1 = xp[(uint32_t)pi.y & 0xffffu], gb1 = xp[(uint32_t)pi.y >> 16];
    const uint32_t ga2 = xp[(uint32_t)pi.z & 0xffffu], gb2 = xp[(uint32_t)pi.z >> 16];
    const uint32_t ga3 = xp[(uint32_t)pi.w & 0xffffu], gb3 = xp[(uint32_t)pi.w >> 16];

    f32x4 res0, res1;
    {
      const float a0 = bf_lo(ga0), b0v = bf_lo(gb0);
      const float a1 = bf_hi(ga0), b1v = bf_hi(gb0);
      res0.x = fmaf(fmaf(c0.w, a0, c0.z), b0v, fmaf(c0.y, a0, c0.x));
      res1.x = fmaf(fmaf(c0.w, a1, c0.z), b1v, fmaf(c0.y, a1, c0.x));
    }
    {
      const float a0 = bf_lo(ga1), b0v = bf_lo(gb1);
      const float a1 = bf_hi(ga1), b1v = bf_hi(gb1);
      res0.y = fmaf(fmaf(c1.w, a0, c1.z), b0v, fmaf(c1.y, a0, c1.x));
      res1.y = fmaf(fmaf(c1.w, a1, c1.z), b1v, fmaf(c1.y, a1, c1.x));
    }
    {
      const float a0 = bf_lo(ga2), b0v = bf_lo(gb2);
      const float a1 = bf_hi(ga2), b1v = bf_hi(gb2);
      res0.z = fmaf(fmaf(c2.w, a0, c2.z), b0v, fmaf(c2.y, a0, c2.x));
      res1.z = fmaf(fmaf(c2.w, a1, c2.z), b1v, fmaf(c2.y, a1, c2.x));
    }
    {
      const float a0 = bf_lo(ga3), b0v = bf_lo(gb3);
      const float a1 = bf_hi(ga3), b1v = bf_hi(gb3);
      res0.w = fmaf(fmaf(c3.w, a0, c3.z), b0v, fmaf(c3.y, a0, c3.x));
      res1.w = fmaf(fmaf(c3.w, a1, c3.z), b1v, fmaf(c3.y, a1, c3.x));
    }

    __builtin_nontemporal_store(
        res0, reinterpret_cast<f32x4*>(out + (size_t)b0 * OUT_DIM + o));
    __builtin_nontemporal_store(
        res1, reinterpret_cast<f32x4*>(out + (size_t)(b0 + 1) * OUT_DIM + o));
  }
}

extern "C" void kernel_launch(void* const* d_in, const int* in_sizes, int n_in,
                              void* d_out, int out_size, void* d_ws, size_t ws_size,
                              hipStream_t stream) {
  const float* x       = (const float*)d_in[0];
  const float* weights = (const float*)d_in[1];
  const int*   idx_a   = (const int*)d_in[2];
  const int*   idx_b   = (const int*)d_in[3];
  float*       out     = (float*)d_out;

  float4*   coef = (float4*)d_ws;                         // 256 KB
  uint32_t* pidx = (uint32_t*)((char*)d_ws + (size_t)OUT_DIM * 16);  // +64 KB

  coef_kernel<<<OUT_DIM / 256, 256, 0, stream>>>(weights, idx_a, idx_b, coef, pidx);
  logic_main<<<NBLK, THREADS, 0, stream>>>(x, coef, pidx, out);
}